// Round 2
// baseline (533.040 us; speedup 1.0000x reference)
//
#include <hip/hip_runtime.h>
#include <stdint.h>

#define NB 8
#define NC 256
#define NE 128
#define NHW 4096

typedef __bf16 v8bf __attribute__((ext_vector_type(8)));
typedef float v4f __attribute__((ext_vector_type(4)));
typedef float v16f __attribute__((ext_vector_type(16)));

#if __has_builtin(__builtin_amdgcn_exp2f)
#define EXP2F(x) __builtin_amdgcn_exp2f(x)
#else
#define EXP2F(x) exp2f(x)
#endif

// fp32 -> bf16 round-to-nearest-even (bit trick; finite inputs only)
__device__ __forceinline__ unsigned short f2bf(float x) {
    union { float f; unsigned int u; } v; v.f = x;
    unsigned int r = v.u + 0x7fffu + ((v.u >> 16) & 1u);
    return (unsigned short)(r >> 16);
}

// ---------------- K0: cast weights to bf16. Wbf[e][c], e<128 = w_theta * (scale*log2e), e>=128 = w_phi
__global__ __launch_bounds__(256) void cast_w_kernel(const float* __restrict__ wt,
                                                     const float* __restrict__ wp,
                                                     unsigned short* __restrict__ Wbf) {
    int i = blockIdx.x * 256 + threadIdx.x;                 // 0..65535
    const float QS = 0.08838834764831845f * 1.4426950408889634f; // 1/sqrt(128) * log2(e)
    float v = (i < 32768) ? wt[i] * QS : wp[i - 32768];
    Wbf[i] = f2bf(v);
}

// ---------------- K1: cast l -> bf16 (this IS V^T in PV B-operand layout: rows c, contiguous k)
__global__ __launch_bounds__(256) void cast_v_kernel(const float* __restrict__ l,
                                                     unsigned short* __restrict__ Vbf) {
    int i = blockIdx.x * 256 + threadIdx.x;                 // float4 index, 2,097,152 total
    float4 v = ((const float4*)l)[i];
    ushort4 o;
    o.x = f2bf(v.x); o.y = f2bf(v.y); o.z = f2bf(v.z); o.w = f2bf(v.w);
    ((ushort4*)Vbf)[i] = o;
}

// ---------------- K2: projection. Per block: batch b, 64-q tile.
// Q[b][q][e] = sum_c l[b][c][q] * Wtheta[e][c] (pre-scaled), K likewise with Wphi.
__global__ __launch_bounds__(256, 2) void proj_kernel(const float* __restrict__ l,
                                                      const unsigned short* __restrict__ Wbf,
                                                      unsigned short* __restrict__ Qbf,
                                                      unsigned short* __restrict__ Kbf) {
    __shared__ __align__(16) unsigned short A[64][264];     // [q][c], +8 pad, 33792 B
    const int tid = threadIdx.x;
    const int b = blockIdx.x & 7;
    const int qt = (blockIdx.x >> 3) << 6;
    const float* lb = l + (b * NC * NHW + qt);

    for (int s = 0; s < 16; ++s) {
        int f = tid + s * 256;
        int c = f >> 4, j = f & 15;
        float4 v = *(const float4*)(lb + c * NHW + j * 4);
        A[j * 4 + 0][c] = f2bf(v.x);
        A[j * 4 + 1][c] = f2bf(v.y);
        A[j * 4 + 2][c] = f2bf(v.z);
        A[j * 4 + 3][c] = f2bf(v.w);
    }
    __syncthreads();

    const int w = tid >> 6, L = tid & 63;
    const int l15 = L & 15, q4 = L >> 4;
    const v4f vz = {0.f, 0.f, 0.f, 0.f};
    v4f acc[4][4];
    for (int mt = 0; mt < 4; ++mt)
        for (int nt = 0; nt < 4; ++nt) acc[mt][nt] = vz;

    for (int kf = 0; kf < 8; ++kf) {
        int kc = kf * 32 + q4 * 8;
        v8bf a[4], bb[4];
        for (int mt = 0; mt < 4; ++mt)
            a[mt] = *(const v8bf*)&A[mt * 16 + l15][kc];
        for (int nt = 0; nt < 4; ++nt)
            bb[nt] = *(const v8bf*)(Wbf + (w * 64 + nt * 16 + l15) * 256 + kc);
        for (int mt = 0; mt < 4; ++mt)
            for (int nt = 0; nt < 4; ++nt)
                acc[mt][nt] = __builtin_amdgcn_mfma_f32_16x16x32_bf16(a[mt], bb[nt], acc[mt][nt], 0, 0, 0);
    }

    unsigned short* dst = (w < 2) ? Qbf : Kbf;
    const int ebase = (w & 1) * 64;
    for (int mt = 0; mt < 4; ++mt)
        for (int nt = 0; nt < 4; ++nt)
            for (int r = 0; r < 4; ++r) {
                int q = qt + mt * 16 + q4 * 4 + r;
                int e = ebase + nt * 16 + l15;
                dst[(b * NHW + q) * NE + e] = f2bf(acc[mt][nt][r]);
            }
}

// ---------------- K3: flash attention, 32x32x16 MFMA, q-tile 128, k-tile 64.
// 4 waves: QK phase wave=(q-half, k-half); PV phase wave=64-c slice.
// LDS 64KB exactly: Ku[64][128] swz (16K) | Vu[256][64] swz (32K) | Pu[128][64] swz (16K).
// XOR swizzle on 16B units: phys_u = u ^ (row & 7) -> bank-balanced b128 access.
__global__ __launch_bounds__(256, 1) void attn_kernel(const unsigned short* __restrict__ Qbf,
                                                      const unsigned short* __restrict__ Kbf,
                                                      const unsigned short* __restrict__ Vbf,
                                                      float* __restrict__ out) {
    __shared__ __align__(16) unsigned char smem[65536];
    unsigned short* Ku = (unsigned short*)smem;             // [64][128]
    unsigned short* Vu = (unsigned short*)(smem + 16384);   // [256][64]
    unsigned short* Pu = (unsigned short*)(smem + 49152);   // [128][64]
    float* lsum = (float*)(smem + 49152);                   // epilogue overlay: [2][128]
    float* Ot = (float*)smem;                               // epilogue overlay: [64][132]

    const int tid = threadIdx.x;
    const int b = blockIdx.x & 7;                           // batch -> XCD round-robin
    const int qt = (blockIdx.x >> 3) << 7;                  // 128-q tile
    const int w = tid >> 6;
    const int L = tid & 63;
    const int l31 = L & 31, hi = L >> 5;
    const int qh = w & 1, kh = w >> 1;                      // QK-phase roles

    const unsigned short* Qb = Qbf + ((size_t)(b * NHW + qt)) * NE;
    const unsigned short* Kb = Kbf + (size_t)b * NHW * NE;
    const unsigned short* Vb = Vbf + (size_t)b * NC * NHW;

    // Q A-frags in regs: A[m=lane&31][k=(lane>>5)*8+j]; 2 m-tiles x 8 e-frags
    v8bf aq[2][8];
#pragma unroll
    for (int mq = 0; mq < 2; ++mq)
#pragma unroll
        for (int kf = 0; kf < 8; ++kf)
            aq[mq][kf] = *(const v8bf*)(Qb + (qh * 64 + mq * 32 + l31) * NE + kf * 16 + hi * 8);

    // prefetch registers (tile i+1 loaded during iter i)
    uint4 pk[4], pv[8];
#define LOAD_TILE(k0)                                                          \
    {                                                                          \
        _Pragma("unroll") for (int s = 0; s < 4; ++s) {                        \
            int idx = tid + s * 256, r = idx >> 4, c8 = idx & 15;              \
            pk[s] = *(const uint4*)(Kb + (size_t)((k0) + r) * NE + c8 * 8);    \
        }                                                                      \
        _Pragma("unroll") for (int s = 0; s < 8; ++s) {                        \
            int idx = tid + s * 256, c = idx >> 3, c8 = idx & 7;               \
            pv[s] = *(const uint4*)(Vb + (size_t)c * NHW + (k0) + c8 * 8);     \
        }                                                                      \
    }

    LOAD_TILE(0);

    v16f o[4][2];
#pragma unroll
    for (int mt = 0; mt < 4; ++mt)
#pragma unroll
        for (int nl = 0; nl < 2; ++nl)
#pragma unroll
            for (int r = 0; r < 16; ++r) o[mt][nl][r] = 0.f;
    float lacc[32];
#pragma unroll
    for (int i = 0; i < 32; ++i) lacc[i] = 0.f;

    for (int it = 0; it < 64; ++it) {
        __syncthreads();                                    // B1: prev reads done
        // write staged tile to LDS (swizzled)
#pragma unroll
        for (int s = 0; s < 4; ++s) {
            int idx = tid + s * 256, r = idx >> 4, c8 = idx & 15;
            *(uint4*)&Ku[r * 128 + ((c8 ^ (r & 7)) * 8)] = pk[s];
        }
#pragma unroll
        for (int s = 0; s < 8; ++s) {
            int idx = tid + s * 256, c = idx >> 3, c8 = idx & 7;
            *(uint4*)&Vu[c * 64 + ((c8 ^ (c & 7)) * 8)] = pv[s];
        }
        // issue next tile's global loads (latency hidden across this iter)
        int knext = ((it + 1) & 63) << 6;
        LOAD_TILE(knext);
        __syncthreads();                                    // B2: LDS visible

        // ---- QK: S[32q x 32k] per m-tile; wave covers (q-half, k-half)
        v8bf bk[8];
        {
            int kp = kh * 32 + l31;
            int sw = (kp & 7);
#pragma unroll
            for (int kf = 0; kf < 8; ++kf)
                bk[kf] = *(const v8bf*)&Ku[kp * 128 + (((kf * 2 + hi) ^ sw) * 8)];
        }
#pragma unroll
        for (int mt = 0; mt < 2; ++mt) {
            v16f s;
#pragma unroll
            for (int r = 0; r < 16; ++r) s[r] = 0.f;
#pragma unroll
            for (int kf = 0; kf < 8; ++kf)
                s = __builtin_amdgcn_mfma_f32_32x32x16_bf16(aq[mt][kf], bk[kf], s, 0, 0, 0);
            // P = 2^S; C/D: col=lane&31 (kpos), row=(r&3)+8*(r>>2)+4*hi (q)
#pragma unroll
            for (int r = 0; r < 16; ++r) {
                float p = EXP2F(s[r]);
                lacc[mt * 16 + r] += p;
                int q = qh * 64 + mt * 32 + (r & 3) + 8 * (r >> 2) + 4 * hi;
                int col = kh * 32 + l31;
                Pu[q * 64 + (((col >> 3) ^ (q & 7)) * 8) + (col & 7)] = f2bf(p);
            }
        }
        __syncthreads();                                    // B3: P visible

        // ---- PV: wave owns c-slice [64w, 64w+64); all 128 q, all 64 k
        v8bf bv[2][4];
#pragma unroll
        for (int nl = 0; nl < 2; ++nl) {
            int c = w * 64 + nl * 32 + l31;
            int sw = (c & 7);
#pragma unroll
            for (int kf = 0; kf < 4; ++kf)
                bv[nl][kf] = *(const v8bf*)&Vu[c * 64 + (((kf * 2 + hi) ^ sw) * 8)];
        }
#pragma unroll
        for (int mt = 0; mt < 4; ++mt) {
            v8bf ap[4];
            int q = mt * 32 + l31;
            int sw = (q & 7);
#pragma unroll
            for (int kf = 0; kf < 4; ++kf)
                ap[kf] = *(const v8bf*)&Pu[q * 64 + (((kf * 2 + hi) ^ sw) * 8)];
#pragma unroll
            for (int nl = 0; nl < 2; ++nl)
#pragma unroll
                for (int kf = 0; kf < 4; ++kf)
                    o[mt][nl] = __builtin_amdgcn_mfma_f32_32x32x16_bf16(ap[kf], bv[nl][kf], o[mt][nl], 0, 0, 0);
        }
    }
    __syncthreads();                                        // last PV reads done; Pu reusable

    // ---- row sums: butterfly over the 32 columns (lane&31), hi preserved
#pragma unroll
    for (int i = 0; i < 32; ++i) {
        float v = lacc[i];
        v += __shfl_xor(v, 1);
        v += __shfl_xor(v, 2);
        v += __shfl_xor(v, 4);
        v += __shfl_xor(v, 8);
        v += __shfl_xor(v, 16);
        lacc[i] = v;
    }
    if (l31 == 0) {
#pragma unroll
        for (int mt = 0; mt < 2; ++mt)
#pragma unroll
            for (int r = 0; r < 16; ++r) {
                int q = qh * 64 + mt * 32 + (r & 3) + 8 * (r >> 2) + 4 * hi;
                lsum[kh * 128 + q] = lacc[mt * 16 + r];
            }
    }
    __syncthreads();

    // ---- epilogue: 4 phases; wave ph transposes its 64c x 128q slice, all copy out
    for (int ph = 0; ph < 4; ++ph) {
        if (w == ph) {
#pragma unroll
            for (int mt = 0; mt < 4; ++mt)
#pragma unroll
                for (int r = 0; r < 16; ++r) {
                    int q = mt * 32 + (r & 3) + 8 * (r >> 2) + 4 * hi;
                    float li = 1.0f / (lsum[q] + lsum[128 + q]);
#pragma unroll
                    for (int nl = 0; nl < 2; ++nl) {
                        int cc = nl * 32 + l31;
                        Ot[cc * 132 + q] = o[mt][nl][r] * li;
                    }
                }
        }
        __syncthreads();
        float* ob = out + ((size_t)(b * NC + ph * 64)) * NHW + qt;
#pragma unroll
        for (int s = 0; s < 8; ++s) {
            int idx = tid + s * 256, cc = idx >> 5, j = idx & 31;
            *(float4*)&ob[(size_t)cc * NHW + j * 4] = *(const float4*)&Ot[cc * 132 + j * 4];
        }
        __syncthreads();
    }
}

extern "C" void kernel_launch(void* const* d_in, const int* in_sizes, int n_in,
                              void* d_out, int out_size, void* d_ws, size_t ws_size,
                              hipStream_t stream) {
    const float* l  = (const float*)d_in[0];
    const float* wt = (const float*)d_in[1];
    const float* wp = (const float*)d_in[2];
    float* out = (float*)d_out;

    char* ws = (char*)d_ws;
    unsigned short* Wbf = (unsigned short*)ws;                          // 131072 B
    unsigned short* Qbf = (unsigned short*)(ws + 131072);               // 8 MB
    unsigned short* Kbf = (unsigned short*)(ws + 131072 + 8388608);     // 8 MB
    unsigned short* Vbf = (unsigned short*)(ws + 131072 + 16777216);    // 16 MB

    hipLaunchKernelGGL(cast_w_kernel, dim3(256),  dim3(256), 0, stream, wt, wp, Wbf);
    hipLaunchKernelGGL(cast_v_kernel, dim3(8192), dim3(256), 0, stream, l, Vbf);
    hipLaunchKernelGGL(proj_kernel,   dim3(512),  dim3(256), 0, stream, l, Wbf, Qbf, Kbf);
    hipLaunchKernelGGL(attn_kernel,   dim3(256),  dim3(256), 0, stream, Qbf, Kbf, Vbf, out);
}

// Round 3
// 386.187 us; speedup vs baseline: 1.3803x; 1.3803x over previous
//
#include <hip/hip_runtime.h>
#include <stdint.h>

#define NB 8
#define NC 256
#define NE 128
#define NHW 4096

typedef __bf16 v8bf __attribute__((ext_vector_type(8)));
typedef float v4f __attribute__((ext_vector_type(4)));
typedef float v16f __attribute__((ext_vector_type(16)));
typedef unsigned int v4u __attribute__((ext_vector_type(4)));

#if __has_builtin(__builtin_amdgcn_exp2f)
#define EXP2F(x) __builtin_amdgcn_exp2f(x)
#else
#define EXP2F(x) exp2f(x)
#endif

// fp32 -> bf16 round-to-nearest-even (bit trick; finite inputs only)
__device__ __forceinline__ unsigned short f2bf(float x) {
    union { float f; unsigned int u; } v; v.f = x;
    unsigned int r = v.u + 0x7fffu + ((v.u >> 16) & 1u);
    return (unsigned short)(r >> 16);
}

// ---------------- K0: cast weights to bf16. Wbf[e][c], e<128 = w_theta * (scale*log2e), e>=128 = w_phi
__global__ __launch_bounds__(256) void cast_w_kernel(const float* __restrict__ wt,
                                                     const float* __restrict__ wp,
                                                     unsigned short* __restrict__ Wbf) {
    int i = blockIdx.x * 256 + threadIdx.x;                 // 0..65535
    const float QS = 0.08838834764831845f * 1.4426950408889634f; // 1/sqrt(128) * log2(e)
    float v = (i < 32768) ? wt[i] * QS : wp[i - 32768];
    Wbf[i] = f2bf(v);
}

// ---------------- K1: projection (+ fused V cast). Per block: batch b, 64-q tile.
// Q[b][q][e] = sum_c l[b][c][q] * Wtheta[e][c] (pre-scaled), K with Wphi; Vbf = bf16(l).
__global__ __launch_bounds__(256, 2) void proj_kernel(const float* __restrict__ l,
                                                      const unsigned short* __restrict__ Wbf,
                                                      unsigned short* __restrict__ Qbf,
                                                      unsigned short* __restrict__ Kbf,
                                                      unsigned short* __restrict__ Vbf) {
    __shared__ __align__(16) unsigned short A[64][264];     // [q][c], +8 pad, 33792 B
    const int tid = threadIdx.x;
    const int b = blockIdx.x & 7;
    const int qt = (blockIdx.x >> 3) << 6;
    const float* lb = l + ((size_t)b * NC * NHW + qt);

    for (int s = 0; s < 16; ++s) {
        int f = tid + s * 256;
        int c = f >> 4, j = f & 15;
        float4 v = *(const float4*)(lb + (size_t)c * NHW + j * 4);
        ushort4 o4;
        o4.x = f2bf(v.x); o4.y = f2bf(v.y); o4.z = f2bf(v.z); o4.w = f2bf(v.w);
        A[j * 4 + 0][c] = o4.x;
        A[j * 4 + 1][c] = o4.y;
        A[j * 4 + 2][c] = o4.z;
        A[j * 4 + 3][c] = o4.w;
        // fused cast_v: Vbf[b][c][qt + j*4 .. +4]
        *(ushort4*)(Vbf + (size_t)b * NC * NHW + (size_t)c * NHW + qt + j * 4) = o4;
    }
    __syncthreads();

    const int w = tid >> 6, L = tid & 63;
    const int l15 = L & 15, q4 = L >> 4;
    const v4f vz = {0.f, 0.f, 0.f, 0.f};
    v4f acc[4][4];
    for (int mt = 0; mt < 4; ++mt)
        for (int nt = 0; nt < 4; ++nt) acc[mt][nt] = vz;

    for (int kf = 0; kf < 8; ++kf) {
        int kc = kf * 32 + q4 * 8;
        v8bf a[4], bb[4];
        for (int mt = 0; mt < 4; ++mt)
            a[mt] = *(const v8bf*)&A[mt * 16 + l15][kc];
        for (int nt = 0; nt < 4; ++nt)
            bb[nt] = *(const v8bf*)(Wbf + (w * 64 + nt * 16 + l15) * 256 + kc);
        for (int mt = 0; mt < 4; ++mt)
            for (int nt = 0; nt < 4; ++nt)
                acc[mt][nt] = __builtin_amdgcn_mfma_f32_16x16x32_bf16(a[mt], bb[nt], acc[mt][nt], 0, 0, 0);
    }

    unsigned short* dst = (w < 2) ? Qbf : Kbf;
    const int ebase = (w & 1) * 64;
    for (int mt = 0; mt < 4; ++mt)
        for (int nt = 0; nt < 4; ++nt)
            for (int r = 0; r < 4; ++r) {
                int q = qt + mt * 16 + q4 * 4 + r;
                int e = ebase + nt * 16 + l15;
                dst[((size_t)b * NHW + q) * NE + e] = f2bf(acc[mt][nt][r]);
            }
}

// ---------------- K2: flash attention. 32x32x16 MFMA. q-tile 64/block, k-tile 64.
// Waves: qh = w>>1 (q 32-slice), kh = w&1 (k 32-half). S^T = K*Q^T (A=K from LDS,
// B=Q in regs); P^T built IN REGISTERS from S^T C/D via one lane^32 exchange;
// O^T = V*P^T (A=V from LDS, B=P^T regs). No P LDS round-trip, 2 barriers/iter.
// LDS: Ku[64][128] xor16-swz (16K) | Vu[256][64] xor8-swz (32K) = 48K -> 2 blocks/CU.
__global__ __launch_bounds__(256, 2) void attn_kernel(const unsigned short* __restrict__ Qbf,
                                                      const unsigned short* __restrict__ Kbf,
                                                      const unsigned short* __restrict__ Vbf,
                                                      float* __restrict__ out) {
    __shared__ __align__(16) unsigned char smem[49152];
    unsigned short* Ku = (unsigned short*)smem;             // [64][128] swizzled
    unsigned short* Vu = (unsigned short*)(smem + 16384);   // [256][64] swizzled

    const int tid = threadIdx.x;
    const int b = blockIdx.x & 7;                           // batch -> XCD for L2 locality
    const int qt = (blockIdx.x >> 3) << 6;                  // 64-q tile
    const int w = tid >> 6;
    const int L = tid & 63;
    const int l31 = L & 31, hi = L >> 5;
    const int qh = w >> 1, kh = w & 1;

    const unsigned short* Kb = Kbf + (size_t)b * NHW * NE;
    const unsigned short* Vb = Vbf + (size_t)b * NC * NHW;

    // Q B-frags (regs, whole kernel): B[k=e][n=q], n=lane&31 -> q row; e = ef*16+hi*8+j
    v8bf bq[8];
    {
        const unsigned short* qrow = Qbf + ((size_t)b * NHW + qt + qh * 32 + l31) * NE + hi * 8;
#pragma unroll
        for (int ef = 0; ef < 8; ++ef)
            bq[ef] = *(const v8bf*)(qrow + ef * 16);
    }

    v16f o[8];
#pragma unroll
    for (int ct = 0; ct < 8; ++ct)
#pragma unroll
        for (int r = 0; r < 16; ++r) o[ct][r] = 0.f;
    float lacc = 0.f;

    const int x15 = l31 & 15, x7 = l31 & 7;

    for (int it = 0; it < 64; ++it) {
        const int k0 = it << 6;
        __syncthreads();                                    // prev iter's LDS reads done
        // stage K tile [64 k][128 e], 16B-unit xor swizzle by row&15
#pragma unroll
        for (int s = 0; s < 4; ++s) {
            int idx = tid + s * 256, r = idx >> 4, c8 = idx & 15;
            *(uint4*)&Ku[r * 128 + ((c8 ^ (r & 15)) * 8)] =
                *(const uint4*)(Kb + (size_t)(k0 + r) * NE + c8 * 8);
        }
        // stage V tile [256 c][64 k], 16B-unit xor swizzle by row&7
#pragma unroll
        for (int s = 0; s < 8; ++s) {
            int idx = tid + s * 256, c = idx >> 3, u = idx & 7;
            *(uint4*)&Vu[c * 64 + ((u ^ (c & 7)) * 8)] =
                *(const uint4*)(Vb + (size_t)c * NHW + k0 + u * 8);
        }
        __syncthreads();                                    // tile visible

        // ---- QK: S^T (k rows = kh*32.., q cols = qh*32..), 8 MFMAs
        v16f s;
#pragma unroll
        for (int r = 0; r < 16; ++r) s[r] = 0.f;
        {
            const unsigned short* krow = Ku + (kh * 32 + l31) * 128;
#pragma unroll
            for (int ef = 0; ef < 8; ++ef) {
                v8bf ak = *(const v8bf*)(krow + (((2 * ef + hi) ^ x15) * 8));
                s = __builtin_amdgcn_mfma_f32_32x32x16_bf16(ak, bq[ef], s, 0, 0, 0);
            }
        }

        // ---- softmax: p = 2^s (scale*log2e folded into Q); row-sum partial per q-col
        float p[16];
#pragma unroll
        for (int r = 0; r < 16; ++r) p[r] = EXP2F(s[r]);
#pragma unroll
        for (int r = 0; r < 16; ++r) lacc += p[r];
        // pack bf16 pairs, exchange lane<->lane^32, assemble P^T B-frags in regs.
        // C/D row R(r)=(r&3)+8*(r>>2)+4*hi; B-frag k=16kf+8hi+j lives at half h=(j>>2)
        // (own if h==hi==0.. pattern below verified element-wise).
        unsigned int pk[8], px[8];
#pragma unroll
        for (int t = 0; t < 8; ++t)
            pk[t] = (unsigned int)f2bf(p[2 * t]) | ((unsigned int)f2bf(p[2 * t + 1]) << 16);
#pragma unroll
        for (int t = 0; t < 8; ++t)
            px[t] = (unsigned int)__shfl_xor((int)pk[t], 32);
        union { v4u u; v8bf b; } f0, f1;
        if (hi == 0) {
            f0.u = (v4u){pk[0], pk[1], px[0], px[1]};
            f1.u = (v4u){pk[4], pk[5], px[4], px[5]};
        } else {
            f0.u = (v4u){px[2], px[3], pk[2], pk[3]};
            f1.u = (v4u){px[6], px[7], pk[6], pk[7]};
        }

        // ---- PV: O^T[c][q] += V * P^T over this kh half, 16 MFMAs
#pragma unroll
        for (int ct = 0; ct < 8; ++ct) {
            const unsigned short* vrow = Vu + (ct * 32 + l31) * 64;
            v8bf a0 = *(const v8bf*)(vrow + (((kh * 4 + hi) ^ x7) * 8));
            v8bf a1 = *(const v8bf*)(vrow + (((kh * 4 + 2 + hi) ^ x7) * 8));
            o[ct] = __builtin_amdgcn_mfma_f32_32x32x16_bf16(a0, f0.b, o[ct], 0, 0, 0);
            o[ct] = __builtin_amdgcn_mfma_f32_32x32x16_bf16(a1, f1.b, o[ct], 0, 0, 0);
        }
    }

    // ---- epilogue: row sums across hi halves + kh wave pair
    float tot = lacc + __shfl_xor(lacc, 32);
    __syncthreads();                                        // all LDS reads done
    float* red = (float*)smem;                              // [4][32]
    if (hi == 0) red[w * 32 + l31] = tot;
    __syncthreads();
    const float inv = 1.0f / (red[(qh * 2) * 32 + l31] + red[(qh * 2 + 1) * 32 + l31]);

    // merge kh pairs: wave kh=1 dumps acc (2 phases of 4 ct = 16KB/pair), kh=0 adds
    float* mrg = (float*)(smem + 1024) + qh * 4096;         // 16KB per pair
#pragma unroll
    for (int ph = 0; ph < 2; ++ph) {
        __syncthreads();
        if (kh == 1) {
#pragma unroll
            for (int ctl = 0; ctl < 4; ++ctl)
#pragma unroll
                for (int rq = 0; rq < 4; ++rq) {
                    v4f q;
#pragma unroll
                    for (int j = 0; j < 4; ++j) q[j] = o[ph * 4 + ctl][rq * 4 + j];
                    *(v4f*)&mrg[((ctl * 4 + rq) * 64 + L) * 4] = q;
                }
        }
        __syncthreads();
        if (kh == 0) {
#pragma unroll
            for (int ctl = 0; ctl < 4; ++ctl)
#pragma unroll
                for (int rq = 0; rq < 4; ++rq) {
                    v4f q = *(const v4f*)&mrg[((ctl * 4 + rq) * 64 + L) * 4];
#pragma unroll
                    for (int j = 0; j < 4; ++j) o[ph * 4 + ctl][rq * 4 + j] += q[j];
                }
        }
    }

    // ---- store: O^T C/D is already [c rows][q cols]; lane q-col -> coalesced dwords
    if (kh == 0) {
        float* ob = out + (size_t)b * NC * NHW + qt + qh * 32 + l31;
#pragma unroll
        for (int ct = 0; ct < 8; ++ct)
#pragma unroll
            for (int r = 0; r < 16; ++r) {
                int c = ct * 32 + (r & 3) + 8 * (r >> 2) + 4 * hi;
                ob[(size_t)c * NHW] = o[ct][r] * inv;
            }
    }
}

extern "C" void kernel_launch(void* const* d_in, const int* in_sizes, int n_in,
                              void* d_out, int out_size, void* d_ws, size_t ws_size,
                              hipStream_t stream) {
    const float* l  = (const float*)d_in[0];
    const float* wt = (const float*)d_in[1];
    const float* wp = (const float*)d_in[2];
    float* out = (float*)d_out;

    char* ws = (char*)d_ws;
    unsigned short* Wbf = (unsigned short*)ws;                          // 131072 B
    unsigned short* Qbf = (unsigned short*)(ws + 131072);               // 8 MB
    unsigned short* Kbf = (unsigned short*)(ws + 131072 + 8388608);     // 8 MB
    unsigned short* Vbf = (unsigned short*)(ws + 131072 + 16777216);    // 16 MB

    hipLaunchKernelGGL(cast_w_kernel, dim3(256), dim3(256), 0, stream, wt, wp, Wbf);
    hipLaunchKernelGGL(proj_kernel,   dim3(512), dim3(256), 0, stream, l, Wbf, Qbf, Kbf, Vbf);
    hipLaunchKernelGGL(attn_kernel,   dim3(512), dim3(256), 0, stream, Qbf, Kbf, Vbf, out);
}